// Round 1
// baseline (307.619 us; speedup 1.0000x reference)
//
#include <hip/hip_runtime.h>

// Problem constants (from reference):
//   z_e:        [B=64, D=64, H=64, W=64] fp32
//   embeddings: [K=512, D=64] fp32
//   out: z_q_st [64,64,64,64] fp32 (= z_q forward) ++ loss (1 fp32)
constexpr int Dc  = 64;
constexpr int Kc  = 512;
constexpr int HWc = 4096;            // H*W
constexpr int Nc  = 64 * HWc;        // B*H*W = 262144 points
constexpr float INV_ELEMS = 1.0f / 16777216.0f;  // 1 / (B*D*H*W)

// ---- kernel 1: per-code squared norms ------------------------------------
__global__ __launch_bounds__(256) void vq_enorm(const float* __restrict__ emb,
                                                float* __restrict__ enorm2) {
    int k = blockIdx.x * blockDim.x + threadIdx.x;   // 0..511
    const float4* e = reinterpret_cast<const float4*>(emb + k * Dc);
    float s0 = 0.f, s1 = 0.f, s2 = 0.f, s3 = 0.f;
#pragma unroll
    for (int i = 0; i < Dc / 4; ++i) {
        float4 v = e[i];
        s0 = fmaf(v.x, v.x, s0);
        s1 = fmaf(v.y, v.y, s1);
        s2 = fmaf(v.z, v.z, s2);
        s3 = fmaf(v.w, v.w, s3);
    }
    enorm2[k] = (s0 + s1) + (s2 + s3);
}

// ---- kernel 2: main VQ ----------------------------------------------------
__global__ __launch_bounds__(256) void vq_main(const float* __restrict__ z_e,
                                               const float* __restrict__ emb,
                                               const float* __restrict__ enorm2,
                                               float* __restrict__ out,
                                               float* __restrict__ acc) {
    const int p  = blockIdx.x * blockDim.x + threadIdx.x;  // point id [0, N)
    const int b  = p >> 12;        // p / 4096
    const int hw = p & 4095;       // p % 4096

    const float* zp = z_e + (size_t)b * Dc * HWc + hw;
    float z[Dc];
#pragma unroll
    for (int d = 0; d < Dc; ++d) z[d] = zp[(size_t)d * HWc];

    float best = 3.4e38f;
    int   bidx = 0;
    for (int k = 0; k < Kc; ++k) {
        const float* ek = emb + k * Dc;   // wave-uniform address -> scalar loads
        float d0 = 0.f, d1 = 0.f, d2 = 0.f, d3 = 0.f;
#pragma unroll
        for (int d = 0; d < Dc; d += 4) {
            d0 = fmaf(ek[d + 0], z[d + 0], d0);
            d1 = fmaf(ek[d + 1], z[d + 1], d1);
            d2 = fmaf(ek[d + 2], z[d + 2], d2);
            d3 = fmaf(ek[d + 3], z[d + 3], d3);
        }
        float dot  = (d0 + d1) + (d2 + d3);
        float dist = fmaf(-2.0f, dot, enorm2[k]);   // ||z||^2 const: argmin-safe
        if (dist < best) { best = dist; bidx = k; } // strict <: first-occurrence tie-break
    }

    // epilogue: gather winning code, write z_q, accumulate squared error
    const float4* eb = reinterpret_cast<const float4*>(emb + bidx * Dc);
    float* op = out + (size_t)b * Dc * HWc + hw;
    float lsum = 0.f;
#pragma unroll
    for (int q = 0; q < Dc / 4; ++q) {
        float4 e4 = eb[q];
        float z0 = z[4 * q + 0], z1 = z[4 * q + 1], z2 = z[4 * q + 2], z3 = z[4 * q + 3];
        op[(size_t)(4 * q + 0) * HWc] = e4.x;
        op[(size_t)(4 * q + 1) * HWc] = e4.y;
        op[(size_t)(4 * q + 2) * HWc] = e4.z;
        op[(size_t)(4 * q + 3) * HWc] = e4.w;
        float f0 = e4.x - z0, f1 = e4.y - z1, f2 = e4.z - z2, f3 = e4.w - z3;
        lsum = fmaf(f0, f0, lsum);
        lsum = fmaf(f1, f1, lsum);
        lsum = fmaf(f2, f2, lsum);
        lsum = fmaf(f3, f3, lsum);
    }

    // block reduction -> single atomic per block
    float v = lsum;
#pragma unroll
    for (int off = 32; off > 0; off >>= 1) v += __shfl_down(v, off);
    __shared__ float red[4];
    const int lane = threadIdx.x & 63;
    const int wid  = threadIdx.x >> 6;
    if (lane == 0) red[wid] = v;
    __syncthreads();
    if (threadIdx.x == 0) {
        float bs = (red[0] + red[1]) + (red[2] + red[3]);
        atomicAdd(acc, bs);
    }
}

// ---- kernel 3: finalize loss ----------------------------------------------
__global__ void vq_finalize(const float* __restrict__ acc, float* __restrict__ out_loss) {
    out_loss[0] = 1.25f * (acc[0] * INV_ELEMS);
}

extern "C" void kernel_launch(void* const* d_in, const int* in_sizes, int n_in,
                              void* d_out, int out_size, void* d_ws, size_t ws_size,
                              hipStream_t stream) {
    const float* z_e = (const float*)d_in[0];
    const float* emb = (const float*)d_in[1];
    float* out = (float*)d_out;

    float* acc    = (float*)d_ws;                       // 4 B accumulator
    float* enorm2 = (float*)((char*)d_ws + 256);        // 512 floats

    hipMemsetAsync(acc, 0, sizeof(float), stream);
    vq_enorm<<<Kc / 256, 256, 0, stream>>>(emb, enorm2);
    vq_main<<<Nc / 256, 256, 0, stream>>>(z_e, emb, enorm2, out, acc);
    vq_finalize<<<1, 1, 0, stream>>>(acc, out + (size_t)Nc * Dc);
}